// Round 2
// baseline (5785.409 us; speedup 1.0000x reference)
//
#include <hip/hip_runtime.h>
#include <hip/hip_bf16.h>

#define N_NODES   100000
#define N_EDGES   1600000
#define NUM_GRAPHS 1000

typedef unsigned int u32;
typedef unsigned short u16;

__device__ __forceinline__ float bf2f(u16 u){ return __uint_as_float(((u32)u)<<16); }
__device__ __forceinline__ float BL(u32 u){ return __uint_as_float(u<<16); }
__device__ __forceinline__ float BH(u32 u){ return __uint_as_float(u&0xffff0000u); }
// dual-dtype scalar load: isbf=1 -> bf16, else f32
__device__ __forceinline__ float ldf(const void* p, size_t i, int isbf){
  return isbf ? bf2f(((const u16*)p)[i]) : ((const float*)p)[i];
}

// ---------------- dtype detector ----------------
__global__ void k_detect(const u32* __restrict__ x, int* __restrict__ flag){
  int t = threadIdx.x; int cnt = 0;
  for (int i = t; i < 256; i += 64){
    u32 w = x[i];
    u32 e = (w >> 7) & 0xffu;
    if (e >= 110u && e <= 137u) cnt++;
  }
  for (int o = 32; o; o >>= 1) cnt += __shfl_xor(cnt, o);
  if (t == 0) *flag = (cnt > 128) ? 1 : 0;
}

// ---------------- fold edge embedding into msg linear ----------------
__global__ void k_prep(const void* __restrict__ eW, const void* __restrict__ eb,
                       const void* __restrict__ mW, const void* __restrict__ mb,
                       float* __restrict__ fw2, float* __restrict__ fb,
                       const int* __restrict__ flagp){
  int isbf = *flagp;
  int l = blockIdx.x, c = threadIdx.x;
  for (int j = 0; j < 16; j++){
    float acc = 0.f;
    for (int k = 0; k < 32; k++)
      acc += ldf(eW, (size_t)j*32 + k, isbf) * ldf(mW, (size_t)(l*96 + 64 + k)*64 + c, isbf);
    fw2[(l*16 + j)*64 + c] = acc;
  }
  float acc = ldf(mb, (size_t)l*64 + c, isbf);
  for (int k = 0; k < 32; k++)
    acc += ldf(eb, k, isbf) * ldf(mW, (size_t)(l*96 + 64 + k)*64 + c, isbf);
  fb[l*64 + c] = acc;
}

// ---------------- node embedding: h = x @ node_W + node_b ----------------
__global__ void k_node_emb(const void* __restrict__ x, const void* __restrict__ nW,
                           const void* __restrict__ nb, float* __restrict__ h,
                           const int* __restrict__ flagp){
  int isbf = *flagp;
  int lane = threadIdx.x & 63;
  int gw = (blockIdx.x*blockDim.x + threadIdx.x) >> 6;
  int nw = (gridDim.x*blockDim.x) >> 6;
  float w[32];
#pragma unroll
  for (int k = 0; k < 32; k++) w[k] = ldf(nW, (size_t)k*64 + lane, isbf);
  float bias = ldf(nb, lane, isbf);
  for (int n = gw; n < N_NODES; n += nw){
    float acc = bias;
    if (isbf){
      const uint4* xr = (const uint4*)((const u16*)x + (size_t)n*32);
#pragma unroll
      for (int q = 0; q < 4; q++){
        uint4 a = xr[q];
        u32 uu[4] = {a.x, a.y, a.z, a.w};
#pragma unroll
        for (int j = 0; j < 4; j++){
          acc = fmaf(BL(uu[j]), w[q*8 + 2*j + 0], acc);
          acc = fmaf(BH(uu[j]), w[q*8 + 2*j + 1], acc);
        }
      }
    } else {
      const float4* xr = (const float4*)((const float*)x + (size_t)n*32);
#pragma unroll
      for (int q = 0; q < 8; q++){
        float4 a = xr[q];
        acc = fmaf(a.x, w[q*4+0], acc); acc = fmaf(a.y, w[q*4+1], acc);
        acc = fmaf(a.z, w[q*4+2], acc); acc = fmaf(a.w, w[q*4+3], acc);
      }
    }
    h[(size_t)n*64 + lane] = acc;
  }
}

// ---------------- in-degree histogram (int) ----------------
__global__ void k_deg(const int* __restrict__ ei, int* __restrict__ deg){
  int i = blockIdx.x*blockDim.x + threadIdx.x;
  int stride = gridDim.x*blockDim.x;
  for (int e = i; e < N_EDGES; e += stride)
    atomicAdd(&deg[ei[N_EDGES + e]], 1);
}

// ---------------- single-block exclusive scan -> row_ptr, cursor, degf ------
__global__ void __launch_bounds__(1024) k_scan(const int* __restrict__ deg,
                       int* __restrict__ rp, int* __restrict__ cursor,
                       float* __restrict__ degf){
  __shared__ int wsum[16];
  const int CH = 98;                       // 98*1024 >= 100000
  int t = threadIdx.x;
  int i0 = t*CH, i1 = i0 + CH; if (i1 > N_NODES) i1 = N_NODES; if (i0 > N_NODES) i0 = N_NODES;
  int s = 0;
  for (int i = i0; i < i1; i++) s += deg[i];
  int own = s, v = s;
#pragma unroll
  for (int o = 1; o < 64; o <<= 1){ int u = __shfl_up(v, o); if ((t & 63) >= o) v += u; }
  if ((t & 63) == 63) wsum[t >> 6] = v;
  __syncthreads();
  if (t == 0){ int r = 0; for (int k = 0; k < 16; k++){ int x = wsum[k]; wsum[k] = r; r += x; } }
  __syncthreads();
  int run = v - own + wsum[t >> 6];        // exclusive prefix of this chunk
  for (int i = i0; i < i1; i++){
    int d = deg[i];
    rp[i] = run; cursor[i] = run; degf[i] = (float)d;
    run += d;
  }
  if (t == 1023) rp[N_NODES] = run;
}

// ---------------- CSR scatter: per-edge (src, edge_id) into dst buckets -----
__global__ void k_scatter(const int* __restrict__ ei, int* __restrict__ cursor,
                          int* __restrict__ src_perm, int* __restrict__ eid_perm){
  int i = blockIdx.x*blockDim.x + threadIdx.x;
  int stride = gridDim.x*blockDim.x;
  for (int e = i; e < N_EDGES; e += stride){
    int d = ei[N_EDGES + e];
    int p = atomicAdd(&cursor[d], 1);
    src_perm[p] = ei[e];
    eid_perm[p] = e;
  }
}

// ---------------- message + gather-aggregate + BN stats (wave per node) -----
__global__ void __launch_bounds__(256) k_msgagg(
    const float* __restrict__ h, const void* __restrict__ ea,
    const int* __restrict__ rp, const int* __restrict__ src_perm,
    const int* __restrict__ eid_perm,
    const void* __restrict__ mW, const float* __restrict__ fw2,
    const float* __restrict__ fb, float* __restrict__ agg,
    float* __restrict__ stats, const int* __restrict__ flagp, int l){
  __shared__ float bs[128];
  if (threadIdx.x < 128) bs[threadIdx.x] = 0.f;
  __syncthreads();
  int isbf = *flagp;
  int lane = threadIdx.x & 63;
  int gw = (blockIdx.x*blockDim.x + threadIdx.x) >> 6;
  int nw = (gridDim.x*blockDim.x) >> 6;
  float w1[64];
#pragma unroll
  for (int k = 0; k < 64; k++) w1[k] = ldf(mW, (size_t)(l*96 + k)*64 + lane, isbf);
  float w2[16];
#pragma unroll
  for (int j = 0; j < 16; j++) w2[j] = fw2[(l*16 + j)*64 + lane];
  float bias = fb[l*64 + lane];
  float s1 = 0.f, s2 = 0.f;
  for (int n = gw; n < N_NODES; n += nw){
    int b0 = rp[n], b1 = rp[n+1];
    float acc = 0.f;
    for (int e = b0; e < b1; e++){
      int src = src_perm[e];
      int eid = eid_perm[e];
      const float4* hr = (const float4*)(h + (size_t)src*64);
      float m0 = bias, m1 = 0.f, m2 = 0.f, m3 = 0.f;
#pragma unroll
      for (int q = 0; q < 4; q++){
        float4 a = hr[4*q+0];
        m0 = fmaf(a.x, w1[16*q+ 0], m0); m0 = fmaf(a.y, w1[16*q+ 1], m0);
        m0 = fmaf(a.z, w1[16*q+ 2], m0); m0 = fmaf(a.w, w1[16*q+ 3], m0);
        float4 b = hr[4*q+1];
        m1 = fmaf(b.x, w1[16*q+ 4], m1); m1 = fmaf(b.y, w1[16*q+ 5], m1);
        m1 = fmaf(b.z, w1[16*q+ 6], m1); m1 = fmaf(b.w, w1[16*q+ 7], m1);
        float4 c = hr[4*q+2];
        m2 = fmaf(c.x, w1[16*q+ 8], m2); m2 = fmaf(c.y, w1[16*q+ 9], m2);
        m2 = fmaf(c.z, w1[16*q+10], m2); m2 = fmaf(c.w, w1[16*q+11], m2);
        float4 d = hr[4*q+3];
        m3 = fmaf(d.x, w1[16*q+12], m3); m3 = fmaf(d.y, w1[16*q+13], m3);
        m3 = fmaf(d.z, w1[16*q+14], m3); m3 = fmaf(d.w, w1[16*q+15], m3);
      }
      if (isbf){
        const uint4* er = (const uint4*)((const u16*)ea + (size_t)eid*16);
        uint4 a = er[0], b = er[1];
        m0 = fmaf(BL(a.x), w2[ 0], m0); m1 = fmaf(BH(a.x), w2[ 1], m1);
        m2 = fmaf(BL(a.y), w2[ 2], m2); m3 = fmaf(BH(a.y), w2[ 3], m3);
        m0 = fmaf(BL(a.z), w2[ 4], m0); m1 = fmaf(BH(a.z), w2[ 5], m1);
        m2 = fmaf(BL(a.w), w2[ 6], m2); m3 = fmaf(BH(a.w), w2[ 7], m3);
        m0 = fmaf(BL(b.x), w2[ 8], m0); m1 = fmaf(BH(b.x), w2[ 9], m1);
        m2 = fmaf(BL(b.y), w2[10], m2); m3 = fmaf(BH(b.y), w2[11], m3);
        m0 = fmaf(BL(b.z), w2[12], m0); m1 = fmaf(BH(b.z), w2[13], m1);
        m2 = fmaf(BL(b.w), w2[14], m2); m3 = fmaf(BH(b.w), w2[15], m3);
      } else {
        const float4* er = (const float4*)((const float*)ea + (size_t)eid*16);
#pragma unroll
        for (int q = 0; q < 4; q++){
          float4 a = er[q];
          m0 = fmaf(a.x, w2[4*q+0], m0); m1 = fmaf(a.y, w2[4*q+1], m1);
          m2 = fmaf(a.z, w2[4*q+2], m2); m3 = fmaf(a.w, w2[4*q+3], m3);
        }
      }
      float m = fmaxf((m0 + m1) + (m2 + m3), 0.f);
      acc += m;
      s1 += m;
      s2 = fmaf(m, m, s2);
    }
    agg[(size_t)n*64 + lane] = acc;
  }
  atomicAdd(&bs[lane], s1);
  atomicAdd(&bs[64 + lane], s2);
  __syncthreads();
  if (threadIdx.x < 128) atomicAdd(&stats[threadIdx.x], bs[threadIdx.x]);
}

// ---------------- BN finalize ----------------
__global__ void k_fin(const float* __restrict__ stats, const void* __restrict__ gamma,
                      const void* __restrict__ beta, float* __restrict__ aff,
                      float cnt_inv, int goff, const int* __restrict__ flagp){
  int isbf = *flagp; int c = threadIdx.x;
  float mu  = stats[c]      * cnt_inv;
  float var = stats[64 + c] * cnt_inv - mu*mu;
  float rs  = rsqrtf(var + 1e-5f);
  float g = ldf(gamma, (size_t)goff + c, isbf);
  float b = ldf(beta,  (size_t)goff + c, isbf);
  aff[c]      = g*rs;
  aff[64 + c] = b - g*mu*rs;
}

// ---------------- fused update: r = relu(h@Wa + agg'@Wb' + deg*tv + b) ------
// message-BN folded into Wb: wb[k] = maff[k]*Wb[k][c], tv = sum_k maff[64+k]*Wb[k][c]
__global__ void __launch_bounds__(256) k_upd(
    const float* __restrict__ h, const float* __restrict__ agg,
    const float* __restrict__ degf, const float* __restrict__ maff,
    const void* __restrict__ uW, const void* __restrict__ ub,
    float* __restrict__ r, float* __restrict__ stats,
    const int* __restrict__ flagp, int l){
  __shared__ float bs[128];
  if (threadIdx.x < 128) bs[threadIdx.x] = 0.f;
  __syncthreads();
  int isbf = *flagp;
  int lane = threadIdx.x & 63;
  int gw = (blockIdx.x*blockDim.x + threadIdx.x) >> 6;
  int nw = (gridDim.x*blockDim.x) >> 6;
  float wa[64], wb[64]; float tv = 0.f;
#pragma unroll
  for (int k = 0; k < 64; k++){
    wa[k] = ldf(uW, (size_t)(l*128 + k)*64 + lane, isbf);
    float wk = ldf(uW, (size_t)(l*128 + 64 + k)*64 + lane, isbf);
    wb[k] = wk * maff[k];
    tv = fmaf(maff[64 + k], wk, tv);
  }
  float bias = ldf(ub, (size_t)l*64 + lane, isbf);
  float s1 = 0.f, s2 = 0.f;
  for (int n = gw; n < N_NODES; n += nw){
    const float4* hr = (const float4*)(h + (size_t)n*64);
    const float4* ar = (const float4*)(agg + (size_t)n*64);
    float a0 = fmaf(degf[n], tv, bias), a1 = 0.f, a2 = 0.f, a3 = 0.f;
#pragma unroll
    for (int q = 0; q < 8; q++){
      float4 a = hr[2*q+0];
      a0 = fmaf(a.x, wa[8*q+0], a0); a0 = fmaf(a.y, wa[8*q+1], a0);
      a0 = fmaf(a.z, wa[8*q+2], a0); a0 = fmaf(a.w, wa[8*q+3], a0);
      float4 b = hr[2*q+1];
      a1 = fmaf(b.x, wa[8*q+4], a1); a1 = fmaf(b.y, wa[8*q+5], a1);
      a1 = fmaf(b.z, wa[8*q+6], a1); a1 = fmaf(b.w, wa[8*q+7], a1);
      float4 c = ar[2*q+0];
      a2 = fmaf(c.x, wb[8*q+0], a2); a2 = fmaf(c.y, wb[8*q+1], a2);
      a2 = fmaf(c.z, wb[8*q+2], a2); a2 = fmaf(c.w, wb[8*q+3], a2);
      float4 d = ar[2*q+1];
      a3 = fmaf(d.x, wb[8*q+4], a3); a3 = fmaf(d.y, wb[8*q+5], a3);
      a3 = fmaf(d.z, wb[8*q+6], a3); a3 = fmaf(d.w, wb[8*q+7], a3);
    }
    float rl = fmaxf((a0 + a1) + (a2 + a3), 0.f);
    r[(size_t)n*64 + lane] = rl;
    s1 += rl;
    s2 = fmaf(rl, rl, s2);
  }
  atomicAdd(&bs[lane], s1);
  atomicAdd(&bs[64 + lane], s2);
  __syncthreads();
  if (threadIdx.x < 128) atomicAdd(&stats[threadIdx.x], bs[threadIdx.x]);
}

// ---------------- node BN apply: h = s*r + t ----------------
__global__ void k_norm(const float* __restrict__ r, const float* __restrict__ uaff,
                       float* __restrict__ h){
  int i = blockIdx.x*blockDim.x + threadIdx.x;     // over N_NODES*16 float4s
  if (i >= N_NODES*16) return;
  int c4 = i & 15;
  float4 sq = *(const float4*)(uaff + 4*c4);
  float4 tq = *(const float4*)(uaff + 64 + 4*c4);
  float4 v = ((const float4*)r)[i];
  float4 o;
  o.x = fmaf(sq.x, v.x, tq.x); o.y = fmaf(sq.y, v.y, tq.y);
  o.z = fmaf(sq.z, v.z, tq.z); o.w = fmaf(sq.w, v.w, tq.w);
  ((float4*)h)[i] = o;
}

// ---------------- global add pool (batch sorted -> run accumulation) --------
__global__ void k_pool(const float* __restrict__ h, const int* __restrict__ batch,
                       float* __restrict__ g){
  int lane = threadIdx.x & 63;
  int gw = (blockIdx.x*blockDim.x + threadIdx.x) >> 6;
  int nw = (gridDim.x*blockDim.x) >> 6;
  int chunk = (N_NODES + nw - 1) / nw;
  int n0 = gw*chunk;
  int n1 = n0 + chunk; if (n1 > N_NODES) n1 = N_NODES;
  int cur = -1; float acc = 0.f;
  for (int n = n0; n < n1; n++){
    int b = batch[n];
    float v = h[(size_t)n*64 + lane];
    if (b != cur){
      if (cur >= 0) atomicAdd(&g[(size_t)cur*64 + lane], acc);
      cur = b; acc = v;
    } else acc += v;
  }
  if (cur >= 0) atomicAdd(&g[(size_t)cur*64 + lane], acc);
}

// ---------------- readout ----------------
__global__ void k_read(const float* __restrict__ g, const void* __restrict__ r1W,
                       const void* __restrict__ r1b, const void* __restrict__ r2W,
                       const void* __restrict__ r2b, void* __restrict__ out,
                       const int* __restrict__ flagp){
  int isbf = *flagp;
  int lane = threadIdx.x;
  int gr = blockIdx.x;
  float w[64];
#pragma unroll
  for (int k = 0; k < 64; k++) w[k] = ldf(r1W, (size_t)k*64 + lane, isbf);
  float acc = ldf(r1b, lane, isbf);
  const float4* grow = (const float4*)(g + (size_t)gr*64);
#pragma unroll
  for (int q = 0; q < 16; q++){
    float4 a = grow[q];
    acc = fmaf(a.x, w[4*q+0], acc); acc = fmaf(a.y, w[4*q+1], acc);
    acc = fmaf(a.z, w[4*q+2], acc); acc = fmaf(a.w, w[4*q+3], acc);
  }
  float hid = fmaxf(acc, 0.f);
  float p = hid * ldf(r2W, lane, isbf);
  for (int o = 32; o; o >>= 1) p += __shfl_xor(p, o);
  if (lane == 0){
    float v = p + ldf(r2b, 0, isbf);
    if (isbf) ((__hip_bfloat16*)out)[gr] = __float2bfloat16(v);
    else      ((float*)out)[gr] = v;
  }
}

extern "C" void kernel_launch(void* const* d_in, const int* in_sizes, int n_in,
                              void* d_out, int out_size, void* d_ws, size_t ws_size,
                              hipStream_t stream){
  const void* x    = d_in[0];
  const void* ea   = d_in[1];
  const int*  ei   = (const int*)d_in[2];
  const int*  bt   = (const int*)d_in[3];
  const void* nW   = d_in[4];  const void* nb  = d_in[5];
  const void* eW   = d_in[6];  const void* eb  = d_in[7];
  const void* mW   = d_in[8];  const void* mb  = d_in[9];
  const void* mg   = d_in[10]; const void* mbe = d_in[11];
  const void* uW   = d_in[12]; const void* ub  = d_in[13];
  const void* ug   = d_in[14]; const void* ube = d_in[15];
  const void* r1W  = d_in[16]; const void* r1b = d_in[17];
  const void* r2W  = d_in[18]; const void* r2b = d_in[19];

  float* ws = (float*)d_ws;
  float* h        = ws + 0;           // 6,400,000
  float* r        = ws + 6400000;     // 6,400,000
  float* agg      = ws + 12800000;    // 6,400,000
  float* degf     = ws + 19200000;    //   100,000
  int*   deg_i    = (int*)(ws + 19300000);   // 100,000 (zeroed with g)
  float* g        = ws + 19400000;    //    64,000
  float* mstats   = ws + 19464000;    //       128 (zeroed per layer w/ ustats)
  float* ustats   = ws + 19464128;    //       128
  float* maff     = ws + 19464256;    //       128
  float* uaff     = ws + 19464384;    //       128
  int*   flag     = (int*)(ws + 19464512);
  float* fw2      = ws + 19464528;    //     3,072
  float* fb       = ws + 19467600;    //       192
  int*   row_ptr  = (int*)(ws + 19467792);   // 100,001
  int*   cursor   = (int*)(ws + 19567808);   // 100,000
  int*   src_perm = (int*)(ws + 19667808);   // 1,600,000
  int*   eid_perm = (int*)(ws + 21267808);   // 1,600,000  -> end 22,867,808 fl

  k_detect<<<1, 64, 0, stream>>>((const u32*)x, flag);
  hipMemsetAsync(ws + 19300000, 0, 164000*sizeof(float), stream);   // deg_i + g
  k_prep<<<3, 64, 0, stream>>>(eW, eb, mW, mb, fw2, fb, flag);
  k_node_emb<<<256, 256, 0, stream>>>(x, nW, nb, h, flag);
  k_deg<<<512, 256, 0, stream>>>(ei, deg_i);
  k_scan<<<1, 1024, 0, stream>>>(deg_i, row_ptr, cursor, degf);
  k_scatter<<<512, 256, 0, stream>>>(ei, cursor, src_perm, eid_perm);

  for (int l = 0; l < 3; l++){
    hipMemsetAsync(mstats, 0, 256*sizeof(float), stream);           // mstats+ustats
    k_msgagg<<<2048, 256, 0, stream>>>(h, ea, row_ptr, src_perm, eid_perm,
                                       mW, fw2, fb, agg, mstats, flag, l);
    k_fin<<<1, 64, 0, stream>>>(mstats, mg, mbe, maff, 1.0f/(float)N_EDGES, l*64, flag);
    k_upd<<<1024, 256, 0, stream>>>(h, agg, degf, maff, uW, ub, r, ustats, flag, l);
    k_fin<<<1, 64, 0, stream>>>(ustats, ug, ube, uaff, 1.0f/(float)N_NODES, l*64, flag);
    k_norm<<<(N_NODES*16 + 255)/256, 256, 0, stream>>>(r, uaff, h);
  }

  k_pool<<<128, 256, 0, stream>>>(h, bt, g);
  k_read<<<NUM_GRAPHS, 64, 0, stream>>>(g, r1W, r1b, r2W, r2b, d_out, flag);
}

// Round 3
// 1809.354 us; speedup vs baseline: 3.1975x; 3.1975x over previous
//
#include <hip/hip_runtime.h>
#include <hip/hip_bf16.h>

#define N_NODES   100000
#define N_EDGES   1600000
#define NUM_GRAPHS 1000

typedef unsigned int u32;
typedef unsigned short u16;

typedef __bf16 bf16_t;
typedef bf16_t bf16x8 __attribute__((ext_vector_type(8)));
typedef float  f32x4  __attribute__((ext_vector_type(4)));

__device__ __forceinline__ float bf2f(u16 u){ return __uint_as_float(((u32)u)<<16); }
__device__ __forceinline__ float BL(u32 u){ return __uint_as_float(u<<16); }
__device__ __forceinline__ float BH(u32 u){ return __uint_as_float(u&0xffff0000u); }
// f32 -> bf16 bits, round-to-nearest-even
__device__ __forceinline__ u16 f2bf(float f){
  u32 u = __float_as_uint(f);
  return (u16)((u + 0x7fffu + ((u>>16)&1u)) >> 16);
}
// dual-dtype scalar load: isbf=1 -> bf16, else f32
__device__ __forceinline__ float ldf(const void* p, size_t i, int isbf){
  return isbf ? bf2f(((const u16*)p)[i]) : ((const float*)p)[i];
}

// ---------------- dtype detector ----------------
__global__ void k_detect(const u32* __restrict__ x, int* __restrict__ flag){
  int t = threadIdx.x; int cnt = 0;
  for (int i = t; i < 256; i += 64){
    u32 w = x[i];
    u32 e = (w >> 7) & 0xffu;
    if (e >= 110u && e <= 137u) cnt++;
  }
  for (int o = 32; o; o >>= 1) cnt += __shfl_xor(cnt, o);
  if (t == 0) *flag = (cnt > 128) ? 1 : 0;
}

// ---------------- weight prep: build bf16 Wcol[l][n][96] ----------------
// k 0..63  : msg_W1[k][n]
// k 64..79 : folded edge embedding  sum_k2 edge_W[j][k2]*msg_W2[k2][n]
// k 80     : folded bias (msg_b + edge_b@msg_W2)  -- A pad column is 1.0
// k 81..95 : 0
__global__ void k_prep(const void* __restrict__ eW, const void* __restrict__ eb,
                       const void* __restrict__ mW, const void* __restrict__ mb,
                       u16* __restrict__ Wcol, const int* __restrict__ flagp){
  int isbf = *flagp;
  int l = blockIdx.x, c = threadIdx.x;
  u16* W = Wcol + ((size_t)l*64 + c)*96;
  for (int k = 0; k < 64; k++)
    W[k] = f2bf(ldf(mW, (size_t)(l*96 + k)*64 + c, isbf));
  for (int j = 0; j < 16; j++){
    float acc = 0.f;
    for (int k = 0; k < 32; k++)
      acc += ldf(eW, (size_t)j*32 + k, isbf) * ldf(mW, (size_t)(l*96 + 64 + k)*64 + c, isbf);
    W[64 + j] = f2bf(acc);
  }
  float fbv = ldf(mb, (size_t)l*64 + c, isbf);
  for (int k = 0; k < 32; k++)
    fbv += ldf(eb, k, isbf) * ldf(mW, (size_t)(l*96 + 64 + k)*64 + c, isbf);
  W[80] = f2bf(fbv);
  for (int k = 81; k < 96; k++) W[k] = 0;
}

// ---------------- node embedding: h = x @ node_W + node_b (f32 + bf16) ------
__global__ void k_node_emb(const void* __restrict__ x, const void* __restrict__ nW,
                           const void* __restrict__ nb, float* __restrict__ h,
                           u16* __restrict__ h_bf, const int* __restrict__ flagp){
  int isbf = *flagp;
  int lane = threadIdx.x & 63;
  int gw = (blockIdx.x*blockDim.x + threadIdx.x) >> 6;
  int nw = (gridDim.x*blockDim.x) >> 6;
  float w[32];
#pragma unroll
  for (int k = 0; k < 32; k++) w[k] = ldf(nW, (size_t)k*64 + lane, isbf);
  float bias = ldf(nb, lane, isbf);
  for (int n = gw; n < N_NODES; n += nw){
    float acc = bias;
    if (isbf){
      const uint4* xr = (const uint4*)((const u16*)x + (size_t)n*32);
#pragma unroll
      for (int q = 0; q < 4; q++){
        uint4 a = xr[q];
        u32 uu[4] = {a.x, a.y, a.z, a.w};
#pragma unroll
        for (int j = 0; j < 4; j++){
          acc = fmaf(BL(uu[j]), w[q*8 + 2*j + 0], acc);
          acc = fmaf(BH(uu[j]), w[q*8 + 2*j + 1], acc);
        }
      }
    } else {
      const float4* xr = (const float4*)((const float*)x + (size_t)n*32);
#pragma unroll
      for (int q = 0; q < 8; q++){
        float4 a = xr[q];
        acc = fmaf(a.x, w[q*4+0], acc); acc = fmaf(a.y, w[q*4+1], acc);
        acc = fmaf(a.z, w[q*4+2], acc); acc = fmaf(a.w, w[q*4+3], acc);
      }
    }
    h[(size_t)n*64 + lane] = acc;
    h_bf[(size_t)n*64 + lane] = f2bf(acc);
  }
}

// ---------------- in-degree histogram ----------------
__global__ void k_deg(const int* __restrict__ ei, int* __restrict__ deg){
  int i = blockIdx.x*blockDim.x + threadIdx.x;
  int stride = gridDim.x*blockDim.x;
  for (int e = i; e < N_EDGES; e += stride)
    atomicAdd(&deg[ei[N_EDGES + e]], 1);
}

// ---------------- single-block exclusive scan -> row_ptr, cursor, degf ------
__global__ void __launch_bounds__(1024) k_scan(const int* __restrict__ deg,
                       int* __restrict__ rp, int* __restrict__ cursor,
                       float* __restrict__ degf){
  __shared__ int wsum[16];
  const int CH = 98;
  int t = threadIdx.x;
  int i0 = t*CH, i1 = i0 + CH; if (i1 > N_NODES) i1 = N_NODES; if (i0 > N_NODES) i0 = N_NODES;
  int s = 0;
  for (int i = i0; i < i1; i++) s += deg[i];
  int own = s, v = s;
#pragma unroll
  for (int o = 1; o < 64; o <<= 1){ int u = __shfl_up(v, o); if ((t & 63) >= o) v += u; }
  if ((t & 63) == 63) wsum[t >> 6] = v;
  __syncthreads();
  if (t == 0){ int r = 0; for (int k = 0; k < 16; k++){ int x = wsum[k]; wsum[k] = r; r += x; } }
  __syncthreads();
  int run = v - own + wsum[t >> 6];
  for (int i = i0; i < i1; i++){
    int d = deg[i];
    rp[i] = run; cursor[i] = run; degf[i] = (float)d;
    run += d;
  }
  if (t == 1023) rp[N_NODES] = run;
}

// ---------------- CSR scatter: (src, eid) pairs into dst buckets ----------
__global__ void k_scatter(const int* __restrict__ ei, int* __restrict__ cursor,
                          int* __restrict__ perm2){
  int i = blockIdx.x*blockDim.x + threadIdx.x;
  int stride = gridDim.x*blockDim.x;
  for (int e = i; e < N_EDGES; e += stride){
    int d = ei[N_EDGES + e];
    int p = atomicAdd(&cursor[d], 1);
    ((int2*)perm2)[p] = make_int2(ei[e], e);
  }
}

// ---------------- MFMA message + gather-aggregate + BN stats ----------------
// Wave handles a node-aligned, edge-balanced range. Per 16-edge tile:
// cooperative gather of A rows [h_bf[src](64) | ea(16) | 1.0 | 0...] into LDS,
// 12x mfma 16x16x32 bf16 vs preloaded B frags, relu+mask, per-col stats,
// shuffle-reduce rows -> one plain 256B store per node. No atomics on agg.
__global__ void __launch_bounds__(256) k_msgmm(
    const u16* __restrict__ h_bf, const void* __restrict__ ea,
    const int* __restrict__ rp, const int* __restrict__ perm2,
    const u16* __restrict__ Wcol, float* __restrict__ agg,
    float* __restrict__ stats, const int* __restrict__ flagp,
    int l, int nwaves){
  __shared__ float bs[128];
  __shared__ u32 lds[4*16*52];          // 4 waves x 16 rows x 208B
  int tid = threadIdx.x;
  if (tid < 128) bs[tid] = 0.f;
  int lane = tid & 63, wv = tid >> 6;
  u32* A = lds + wv*16*52;
  int isbf = *flagp;
  // pad init: element 80 = 1.0 bf16 (bias row), 81..95 = 0; never overwritten
  if (lane < 32){
    uint4 z = make_uint4((lane&1)? 0u : 0x3f80u, 0u, 0u, 0u);
    *(uint4*)(A + (lane>>1)*52 + 40 + (lane&1)*4) = z;
  }
  __syncthreads();
  int w = blockIdx.x*4 + wv;
  long long t0 = (long long)w     * N_EDGES / nwaves;
  long long t1 = (long long)(w+1) * N_EDGES / nwaves;
  int lo = 0, hi = N_NODES;
  while (lo < hi){ int mid = (lo+hi)>>1; if ((long long)rp[mid] < t0) lo = mid+1; else hi = mid; }
  int n0 = lo, n1;
  if (w == nwaves-1) n1 = N_NODES;
  else {
    lo = 0; hi = N_NODES;
    while (lo < hi){ int mid = (lo+hi)>>1; if ((long long)rp[mid] < t1) lo = mid+1; else hi = mid; }
    n1 = lo;
  }
  int nn = lane & 15, kg = lane >> 4;
  bf16x8 B[3][4];
  const u16* Wl = Wcol + (size_t)l*64*96;
#pragma unroll
  for (int t = 0; t < 4; t++)
#pragma unroll
    for (int kb = 0; kb < 3; kb++)
      B[kb][t] = *(const bf16x8*)(Wl + (size_t)(t*16+nn)*96 + kb*32 + kg*8);
  float s1[4] = {0,0,0,0}, s2[4] = {0,0,0,0};
  int rA = lane>>3, sA = lane&7;        // h gather: rows 0-7 (+8), 8 x 16B segs
  int rC = lane>>1, sC = lane&1;        // ea gather: lanes<32, 16 rows x 2 segs
  for (int n = n0; n < n1; n++){
    int b0 = rp[n], b1 = rp[n+1];
    float r0 = 0.f, r1 = 0.f, r2 = 0.f, r3 = 0.f;
    for (int base = b0; base < b1; base += 16){
      int rem = b1 - base; if (rem > 16) rem = 16;
      // --- cooperative gather (independent per-lane loads -> high MLP) ---
      int eA = base + (rA < rem ? rA : rem-1);
      int2 pA = ((const int2*)perm2)[eA];
      uint4 vA = ((const uint4*)h_bf)[(size_t)pA.x*8 + sA];
      int rB = rA + 8;
      int eB = base + (rB < rem ? rB : rem-1);
      int2 pB = ((const int2*)perm2)[eB];
      uint4 vB = ((const uint4*)h_bf)[(size_t)pB.x*8 + sA];
      uint4 vC; int doC = (lane < 32);
      if (doC){
        int eC = base + (rC < rem ? rC : rem-1);
        int2 pC = ((const int2*)perm2)[eC];
        if (isbf){
          vC = ((const uint4*)ea)[(size_t)pC.y*2 + sC];
        } else {
          const float4* ef = (const float4*)ea;
          float4 f0 = ef[(size_t)pC.y*4 + sC*2];
          float4 f1 = ef[(size_t)pC.y*4 + sC*2 + 1];
          vC.x = (u32)f2bf(f0.x) | ((u32)f2bf(f0.y)<<16);
          vC.y = (u32)f2bf(f0.z) | ((u32)f2bf(f0.w)<<16);
          vC.z = (u32)f2bf(f1.x) | ((u32)f2bf(f1.y)<<16);
          vC.w = (u32)f2bf(f1.z) | ((u32)f2bf(f1.w)<<16);
        }
      }
      asm volatile("s_waitcnt lgkmcnt(0)" ::: "memory");  // prev frag reads done
      *(uint4*)(A + rA*52 + sA*4) = vA;
      *(uint4*)(A + rB*52 + sA*4) = vB;
      if (doC) *(uint4*)(A + rC*52 + 32 + sC*4) = vC;
      asm volatile("s_waitcnt lgkmcnt(0)" ::: "memory");  // writes visible
      // --- 12 MFMAs: K=96, 4 col-tiles ---
      f32x4 a0 = {0,0,0,0}, a1 = {0,0,0,0}, a2 = {0,0,0,0}, a3 = {0,0,0,0};
#pragma unroll
      for (int kb = 0; kb < 3; kb++){
        bf16x8 af = *(const bf16x8*)(A + nn*52 + kb*16 + kg*4);
        a0 = __builtin_amdgcn_mfma_f32_16x16x32_bf16(af, B[kb][0], a0, 0,0,0);
        a1 = __builtin_amdgcn_mfma_f32_16x16x32_bf16(af, B[kb][1], a1, 0,0,0);
        a2 = __builtin_amdgcn_mfma_f32_16x16x32_bf16(af, B[kb][2], a2, 0,0,0);
        a3 = __builtin_amdgcn_mfma_f32_16x16x32_bf16(af, B[kb][3], a3, 0,0,0);
      }
      // --- relu + row-validity mask + stats + row-sum ---
      int rowbase = kg*4;
      float ts0 = 0.f, ts1 = 0.f, ts2 = 0.f, ts3 = 0.f;
#pragma unroll
      for (int j = 0; j < 4; j++){
        bool valid = (rowbase + j) < rem;
        float m0 = fmaxf(a0[j], 0.f); m0 = valid ? m0 : 0.f;
        float m1 = fmaxf(a1[j], 0.f); m1 = valid ? m1 : 0.f;
        float m2 = fmaxf(a2[j], 0.f); m2 = valid ? m2 : 0.f;
        float m3 = fmaxf(a3[j], 0.f); m3 = valid ? m3 : 0.f;
        ts0 += m0; ts1 += m1; ts2 += m2; ts3 += m3;
        s2[0] = fmaf(m0,m0,s2[0]); s2[1] = fmaf(m1,m1,s2[1]);
        s2[2] = fmaf(m2,m2,s2[2]); s2[3] = fmaf(m3,m3,s2[3]);
      }
      s1[0] += ts0; s1[1] += ts1; s1[2] += ts2; s1[3] += ts3;
      ts0 += __shfl_xor(ts0,16); ts0 += __shfl_xor(ts0,32);
      ts1 += __shfl_xor(ts1,16); ts1 += __shfl_xor(ts1,32);
      ts2 += __shfl_xor(ts2,16); ts2 += __shfl_xor(ts2,32);
      ts3 += __shfl_xor(ts3,16); ts3 += __shfl_xor(ts3,32);
      r0 += ts0; r1 += ts1; r2 += ts2; r3 += ts3;
    }
    float v = (kg==0) ? r0 : (kg==1) ? r1 : (kg==2) ? r2 : r3;   // col = lane
    agg[(size_t)n*64 + lane] = v;
  }
#pragma unroll
  for (int t = 0; t < 4; t++){
    atomicAdd(&bs[t*16+nn], s1[t]);
    atomicAdd(&bs[64+t*16+nn], s2[t]);
  }
  __syncthreads();
  if (tid < 128) atomicAdd(&stats[tid], bs[tid]);
}

// ---------------- BN finalize ----------------
__global__ void k_fin(const float* __restrict__ stats, const void* __restrict__ gamma,
                      const void* __restrict__ beta, float* __restrict__ aff,
                      float cnt_inv, int goff, const int* __restrict__ flagp){
  int isbf = *flagp; int c = threadIdx.x;
  float mu  = stats[c]      * cnt_inv;
  float var = stats[64 + c] * cnt_inv - mu*mu;
  float rs  = rsqrtf(var + 1e-5f);
  float g = ldf(gamma, (size_t)goff + c, isbf);
  float b = ldf(beta,  (size_t)goff + c, isbf);
  aff[c]      = g*rs;
  aff[64 + c] = b - g*mu*rs;
}

// ---------------- fused update (in-place on h): h=relu(h@Wa+agg'@Wb'+...) ---
__global__ void __launch_bounds__(256) k_upd(
    float* __restrict__ h, const float* __restrict__ agg,
    const float* __restrict__ degf, const float* __restrict__ maff,
    const void* __restrict__ uW, const void* __restrict__ ub,
    float* __restrict__ stats, const int* __restrict__ flagp, int l){
  __shared__ float bs[128];
  if (threadIdx.x < 128) bs[threadIdx.x] = 0.f;
  __syncthreads();
  int isbf = *flagp;
  int lane = threadIdx.x & 63;
  int gw = (blockIdx.x*blockDim.x + threadIdx.x) >> 6;
  int nw = (gridDim.x*blockDim.x) >> 6;
  float wa[64], wb[64]; float tv = 0.f;
#pragma unroll
  for (int k = 0; k < 64; k++){
    wa[k] = ldf(uW, (size_t)(l*128 + k)*64 + lane, isbf);
    float wk = ldf(uW, (size_t)(l*128 + 64 + k)*64 + lane, isbf);
    wb[k] = wk * maff[k];
    tv = fmaf(maff[64 + k], wk, tv);
  }
  float bias = ldf(ub, (size_t)l*64 + lane, isbf);
  float s1 = 0.f, s2 = 0.f;
  for (int n = gw; n < N_NODES; n += nw){
    const float4* hr = (const float4*)(h + (size_t)n*64);
    const float4* ar = (const float4*)(agg + (size_t)n*64);
    float a0 = fmaf(degf[n], tv, bias), a1 = 0.f, a2 = 0.f, a3 = 0.f;
#pragma unroll
    for (int q = 0; q < 8; q++){
      float4 a = hr[2*q+0];
      a0 = fmaf(a.x, wa[8*q+0], a0); a0 = fmaf(a.y, wa[8*q+1], a0);
      a0 = fmaf(a.z, wa[8*q+2], a0); a0 = fmaf(a.w, wa[8*q+3], a0);
      float4 b = hr[2*q+1];
      a1 = fmaf(b.x, wa[8*q+4], a1); a1 = fmaf(b.y, wa[8*q+5], a1);
      a1 = fmaf(b.z, wa[8*q+6], a1); a1 = fmaf(b.w, wa[8*q+7], a1);
      float4 c = ar[2*q+0];
      a2 = fmaf(c.x, wb[8*q+0], a2); a2 = fmaf(c.y, wb[8*q+1], a2);
      a2 = fmaf(c.z, wb[8*q+2], a2); a2 = fmaf(c.w, wb[8*q+3], a2);
      float4 d = ar[2*q+1];
      a3 = fmaf(d.x, wb[8*q+4], a3); a3 = fmaf(d.y, wb[8*q+5], a3);
      a3 = fmaf(d.z, wb[8*q+6], a3); a3 = fmaf(d.w, wb[8*q+7], a3);
    }
    float rl = fmaxf((a0 + a1) + (a2 + a3), 0.f);
    h[(size_t)n*64 + lane] = rl;
    s1 += rl;
    s2 = fmaf(rl, rl, s2);
  }
  atomicAdd(&bs[lane], s1);
  atomicAdd(&bs[64 + lane], s2);
  __syncthreads();
  if (threadIdx.x < 128) atomicAdd(&stats[threadIdx.x], bs[threadIdx.x]);
}

// ---------------- node BN apply (in-place) + bf16 dual store ----------------
__global__ void k_norm(float* __restrict__ h, const float* __restrict__ uaff,
                       u16* __restrict__ h_bf){
  int i = blockIdx.x*blockDim.x + threadIdx.x;     // over N_NODES*16 float4s
  if (i >= N_NODES*16) return;
  int c4 = i & 15;
  float4 sq = *(const float4*)(uaff + 4*c4);
  float4 tq = *(const float4*)(uaff + 64 + 4*c4);
  float4 v = ((const float4*)h)[i];
  float4 o;
  o.x = fmaf(sq.x, v.x, tq.x); o.y = fmaf(sq.y, v.y, tq.y);
  o.z = fmaf(sq.z, v.z, tq.z); o.w = fmaf(sq.w, v.w, tq.w);
  ((float4*)h)[i] = o;
  ushort4 ob;
  ob.x = f2bf(o.x); ob.y = f2bf(o.y); ob.z = f2bf(o.z); ob.w = f2bf(o.w);
  ((ushort4*)h_bf)[i] = ob;
}

// ---------------- global add pool (batch sorted -> run accumulation) --------
__global__ void k_pool(const float* __restrict__ h, const int* __restrict__ batch,
                       float* __restrict__ g){
  int lane = threadIdx.x & 63;
  int gw = (blockIdx.x*blockDim.x + threadIdx.x) >> 6;
  int nw = (gridDim.x*blockDim.x) >> 6;
  int chunk = (N_NODES + nw - 1) / nw;
  int n0 = gw*chunk;
  int n1 = n0 + chunk; if (n1 > N_NODES) n1 = N_NODES;
  int cur = -1; float acc = 0.f;
  for (int n = n0; n < n1; n++){
    int b = batch[n];
    float v = h[(size_t)n*64 + lane];
    if (b != cur){
      if (cur >= 0) atomicAdd(&g[(size_t)cur*64 + lane], acc);
      cur = b; acc = v;
    } else acc += v;
  }
  if (cur >= 0) atomicAdd(&g[(size_t)cur*64 + lane], acc);
}

// ---------------- readout ----------------
__global__ void k_read(const float* __restrict__ g, const void* __restrict__ r1W,
                       const void* __restrict__ r1b, const void* __restrict__ r2W,
                       const void* __restrict__ r2b, void* __restrict__ out,
                       const int* __restrict__ flagp){
  int isbf = *flagp;
  int lane = threadIdx.x;
  int gr = blockIdx.x;
  float w[64];
#pragma unroll
  for (int k = 0; k < 64; k++) w[k] = ldf(r1W, (size_t)k*64 + lane, isbf);
  float acc = ldf(r1b, lane, isbf);
  const float4* grow = (const float4*)(g + (size_t)gr*64);
#pragma unroll
  for (int q = 0; q < 16; q++){
    float4 a = grow[q];
    acc = fmaf(a.x, w[4*q+0], acc); acc = fmaf(a.y, w[4*q+1], acc);
    acc = fmaf(a.z, w[4*q+2], acc); acc = fmaf(a.w, w[4*q+3], acc);
  }
  float hid = fmaxf(acc, 0.f);
  float p = hid * ldf(r2W, lane, isbf);
  for (int o = 32; o; o >>= 1) p += __shfl_xor(p, o);
  if (lane == 0){
    float v = p + ldf(r2b, 0, isbf);
    if (isbf) ((__hip_bfloat16*)out)[gr] = __float2bfloat16(v);
    else      ((float*)out)[gr] = v;
  }
}

extern "C" void kernel_launch(void* const* d_in, const int* in_sizes, int n_in,
                              void* d_out, int out_size, void* d_ws, size_t ws_size,
                              hipStream_t stream){
  const void* x    = d_in[0];
  const void* ea   = d_in[1];
  const int*  ei   = (const int*)d_in[2];
  const int*  bt   = (const int*)d_in[3];
  const void* nW   = d_in[4];  const void* nb  = d_in[5];
  const void* eW   = d_in[6];  const void* eb  = d_in[7];
  const void* mW   = d_in[8];  const void* mb  = d_in[9];
  const void* mg   = d_in[10]; const void* mbe = d_in[11];
  const void* uW   = d_in[12]; const void* ub  = d_in[13];
  const void* ug   = d_in[14]; const void* ube = d_in[15];
  const void* r1W  = d_in[16]; const void* r1b = d_in[17];
  const void* r2W  = d_in[18]; const void* r2b = d_in[19];

  float* ws = (float*)d_ws;
  float* h        = ws + 0;                   // 6,400,000
  float* agg      = ws + 6400000;             // 6,400,000
  u16*   h_bf     = (u16*)(ws + 12800000);    // 3,200,000 fl (6.4M u16)
  int*   perm2    = (int*)(ws + 16000000);    // 3,200,000 ints (1.6M int2)
  float* degf     = ws + 19200000;            //   100,000
  int*   deg_i    = (int*)(ws + 19300000);    //   100,000
  float* g        = ws + 19400000;            //    64,000
  float* mstats   = ws + 19464000;            //       128
  float* ustats   = ws + 19464128;            //       128
  float* maff     = ws + 19464256;            //       128
  float* uaff     = ws + 19464384;            //       128
  int*   flag     = (int*)(ws + 19464512);    //        16
  u16*   Wcol     = (u16*)(ws + 19464528);    // 18,432 u16 = 9,216 fl
  int*   row_ptr  = (int*)(ws + 19473744);    //   100,001
  int*   cursor   = (int*)(ws + 19573748);    //   100,000  -> end 19,673,748 fl

  const int MM_BLOCKS = 2048;
  const int MM_WAVES  = MM_BLOCKS * 4;

  k_detect<<<1, 64, 0, stream>>>((const u32*)x, flag);
  hipMemsetAsync(ws + 19300000, 0, 164000*sizeof(float), stream);   // deg_i + g
  k_prep<<<3, 64, 0, stream>>>(eW, eb, mW, mb, Wcol, flag);
  k_node_emb<<<256, 256, 0, stream>>>(x, nW, nb, h, h_bf, flag);
  k_deg<<<512, 256, 0, stream>>>(ei, deg_i);
  k_scan<<<1, 1024, 0, stream>>>(deg_i, row_ptr, cursor, degf);
  k_scatter<<<512, 256, 0, stream>>>(ei, cursor, perm2);

  for (int l = 0; l < 3; l++){
    hipMemsetAsync(mstats, 0, 256*sizeof(float), stream);           // mstats+ustats
    k_msgmm<<<MM_BLOCKS, 256, 0, stream>>>(h_bf, ea, row_ptr, perm2, Wcol,
                                           agg, mstats, flag, l, MM_WAVES);
    k_fin<<<1, 64, 0, stream>>>(mstats, mg, mbe, maff, 1.0f/(float)N_EDGES, l*64, flag);
    k_upd<<<1024, 256, 0, stream>>>(h, agg, degf, maff, uW, ub, ustats, flag, l);
    k_fin<<<1, 64, 0, stream>>>(ustats, ug, ube, uaff, 1.0f/(float)N_NODES, l*64, flag);
    k_norm<<<(N_NODES*16 + 255)/256, 256, 0, stream>>>(h, uaff, h_bf);
  }

  k_pool<<<128, 256, 0, stream>>>(h, bt, g);
  k_read<<<NUM_GRAPHS, 64, 0, stream>>>(g, r1W, r1b, r2W, r2b, d_out, flag);
}

// Round 4
// 1549.517 us; speedup vs baseline: 3.7337x; 1.1677x over previous
//
#include <hip/hip_runtime.h>
#include <hip/hip_bf16.h>

#define N_NODES   100000
#define N_EDGES   1600000
#define NUM_GRAPHS 1000

typedef unsigned int u32;
typedef unsigned short u16;

typedef __bf16 bf16_t;
typedef bf16_t bf16x8 __attribute__((ext_vector_type(8)));
typedef float  f32x4  __attribute__((ext_vector_type(4)));

__device__ __forceinline__ float bf2f(u16 u){ return __uint_as_float(((u32)u)<<16); }
__device__ __forceinline__ float BL(u32 u){ return __uint_as_float(u<<16); }
__device__ __forceinline__ float BH(u32 u){ return __uint_as_float(u&0xffff0000u); }
// f32 -> bf16 bits, round-to-nearest-even
__device__ __forceinline__ u16 f2bf(float f){
  u32 u = __float_as_uint(f);
  return (u16)((u + 0x7fffu + ((u>>16)&1u)) >> 16);
}
// dual-dtype scalar load: isbf=1 -> bf16, else f32
__device__ __forceinline__ float ldf(const void* p, size_t i, int isbf){
  return isbf ? bf2f(((const u16*)p)[i]) : ((const float*)p)[i];
}

// ---------------- dtype detector ----------------
__global__ void k_detect(const u32* __restrict__ x, int* __restrict__ flag){
  int t = threadIdx.x; int cnt = 0;
  for (int i = t; i < 256; i += 64){
    u32 w = x[i];
    u32 e = (w >> 7) & 0xffu;
    if (e >= 110u && e <= 137u) cnt++;
  }
  for (int o = 32; o; o >>= 1) cnt += __shfl_xor(cnt, o);
  if (t == 0) *flag = (cnt > 128) ? 1 : 0;
}

// ---------------- weight prep: build bf16 Wcol[l][n][96] ----------------
__global__ void k_prep(const void* __restrict__ eW, const void* __restrict__ eb,
                       const void* __restrict__ mW, const void* __restrict__ mb,
                       u16* __restrict__ Wcol, const int* __restrict__ flagp){
  int isbf = *flagp;
  int l = blockIdx.x, c = threadIdx.x;
  u16* W = Wcol + ((size_t)l*64 + c)*96;
  for (int k = 0; k < 64; k++)
    W[k] = f2bf(ldf(mW, (size_t)(l*96 + k)*64 + c, isbf));
  for (int j = 0; j < 16; j++){
    float acc = 0.f;
    for (int k = 0; k < 32; k++)
      acc += ldf(eW, (size_t)j*32 + k, isbf) * ldf(mW, (size_t)(l*96 + 64 + k)*64 + c, isbf);
    W[64 + j] = f2bf(acc);
  }
  float fbv = ldf(mb, (size_t)l*64 + c, isbf);
  for (int k = 0; k < 32; k++)
    fbv += ldf(eb, k, isbf) * ldf(mW, (size_t)(l*96 + 64 + k)*64 + c, isbf);
  W[80] = f2bf(fbv);
  for (int k = 81; k < 96; k++) W[k] = 0;
}

// ---------------- node embedding: h = x @ node_W + node_b (f32 + bf16) ------
__global__ void k_node_emb(const void* __restrict__ x, const void* __restrict__ nW,
                           const void* __restrict__ nb, float* __restrict__ h,
                           u16* __restrict__ h_bf, const int* __restrict__ flagp){
  int isbf = *flagp;
  int lane = threadIdx.x & 63;
  int gw = (blockIdx.x*blockDim.x + threadIdx.x) >> 6;
  int nw = (gridDim.x*blockDim.x) >> 6;
  float w[32];
#pragma unroll
  for (int k = 0; k < 32; k++) w[k] = ldf(nW, (size_t)k*64 + lane, isbf);
  float bias = ldf(nb, lane, isbf);
  for (int n = gw; n < N_NODES; n += nw){
    float acc = bias;
    if (isbf){
      const uint4* xr = (const uint4*)((const u16*)x + (size_t)n*32);
#pragma unroll
      for (int q = 0; q < 4; q++){
        uint4 a = xr[q];
        u32 uu[4] = {a.x, a.y, a.z, a.w};
#pragma unroll
        for (int j = 0; j < 4; j++){
          acc = fmaf(BL(uu[j]), w[q*8 + 2*j + 0], acc);
          acc = fmaf(BH(uu[j]), w[q*8 + 2*j + 1], acc);
        }
      }
    } else {
      const float4* xr = (const float4*)((const float*)x + (size_t)n*32);
#pragma unroll
      for (int q = 0; q < 8; q++){
        float4 a = xr[q];
        acc = fmaf(a.x, w[q*4+0], acc); acc = fmaf(a.y, w[q*4+1], acc);
        acc = fmaf(a.z, w[q*4+2], acc); acc = fmaf(a.w, w[q*4+3], acc);
      }
    }
    h[(size_t)n*64 + lane] = acc;
    h_bf[(size_t)n*64 + lane] = f2bf(acc);
  }
}

// ---------------- in-degree histogram ----------------
__global__ void k_deg(const int* __restrict__ ei, int* __restrict__ deg){
  int i = blockIdx.x*blockDim.x + threadIdx.x;
  int stride = gridDim.x*blockDim.x;
  for (int e = i; e < N_EDGES; e += stride)
    atomicAdd(&deg[ei[N_EDGES + e]], 1);
}

// ---------------- multi-block scan: phase 1 (block sums) ----------------
// 196 blocks x 256 thr, 512 elems/block
__global__ void __launch_bounds__(256) k_scan1(const int* __restrict__ deg,
                                               int* __restrict__ bsum){
  __shared__ int wsum[4];
  int b = blockIdx.x, t = threadIdx.x;
  int i0 = b*512 + t;
  int s = 0;
  if (i0 < N_NODES) s += deg[i0];
  if (i0 + 256 < N_NODES) s += deg[i0 + 256];
  for (int o = 32; o; o >>= 1) s += __shfl_xor(s, o);
  if ((t & 63) == 0) wsum[t >> 6] = s;
  __syncthreads();
  if (t == 0) bsum[b] = wsum[0] + wsum[1] + wsum[2] + wsum[3];
}

// ---------------- scan phase 2: exclusive scan of 196 partials ----------------
__global__ void k_scan2(const int* __restrict__ bsum, int* __restrict__ boff,
                        int* __restrict__ rp){
  __shared__ int l[200];
  int t = threadIdx.x;
  if (t < 196) l[t] = bsum[t];
  __syncthreads();
  if (t == 0){
    int r = 0;
    for (int k = 0; k < 196; k++){ int x = l[k]; l[k] = r; r += x; }
    rp[N_NODES] = r;
  }
  __syncthreads();
  if (t < 196) boff[t] = l[t];
}

// ---------------- scan phase 3: local scan + offset -> rp/cursor/degf --------
__global__ void __launch_bounds__(256) k_scan3(const int* __restrict__ deg,
                        const int* __restrict__ boff, int* __restrict__ rp,
                        int* __restrict__ cursor, float* __restrict__ degf){
  __shared__ int wpre[4];
  int b = blockIdx.x, t = threadIdx.x;
  int i0 = b*512 + 2*t;
  int d0 = (i0     < N_NODES) ? deg[i0]     : 0;
  int d1 = (i0 + 1 < N_NODES) ? deg[i0 + 1] : 0;
  int s = d0 + d1;
  int incl = s;
  for (int o = 1; o < 64; o <<= 1){ int u = __shfl_up(incl, o); if ((t & 63) >= o) incl += u; }
  if ((t & 63) == 63) wpre[t >> 6] = incl;
  __syncthreads();
  if (t == 0){ int r = 0; for (int k = 0; k < 4; k++){ int x = wpre[k]; wpre[k] = r; r += x; } }
  __syncthreads();
  int excl = boff[b] + wpre[t >> 6] + incl - s;
  if (i0 < N_NODES){
    rp[i0] = excl; cursor[i0] = excl; degf[i0] = (float)d0;
  }
  if (i0 + 1 < N_NODES){
    rp[i0+1] = excl + d0; cursor[i0+1] = excl + d0; degf[i0+1] = (float)d1;
  }
}

// ---------------- CSR scatter: (src, eid) pairs into dst buckets ----------
__global__ void k_scatter(const int* __restrict__ ei, int* __restrict__ cursor,
                          int* __restrict__ perm2){
  int i = blockIdx.x*blockDim.x + threadIdx.x;
  int stride = gridDim.x*blockDim.x;
  for (int e = i; e < N_EDGES; e += stride){
    int d = ei[N_EDGES + e];
    int p = atomicAdd(&cursor[d], 1);
    ((int2*)perm2)[p] = make_int2(ei[e], e);
  }
}

// ---------------- MFMA message + gather-aggregate + BN stats ----------------
__global__ void __launch_bounds__(256) k_msgmm(
    const u16* __restrict__ h_bf, const void* __restrict__ ea,
    const int* __restrict__ rp, const int* __restrict__ perm2,
    const u16* __restrict__ Wcol, float* __restrict__ agg,
    float* __restrict__ stats, const int* __restrict__ flagp,
    int l, int nwaves){
  __shared__ float bs[128];
  __shared__ u32 lds[4*16*52];          // 4 waves x 16 rows x 208B
  int tid = threadIdx.x;
  if (tid < 128) bs[tid] = 0.f;
  int lane = tid & 63, wv = tid >> 6;
  u32* A = lds + wv*16*52;
  int isbf = *flagp;
  if (lane < 32){
    uint4 z = make_uint4((lane&1)? 0u : 0x3f80u, 0u, 0u, 0u);
    *(uint4*)(A + (lane>>1)*52 + 40 + (lane&1)*4) = z;
  }
  __syncthreads();
  int w = blockIdx.x*4 + wv;
  long long t0 = (long long)w     * N_EDGES / nwaves;
  long long t1 = (long long)(w+1) * N_EDGES / nwaves;
  int lo = 0, hi = N_NODES;
  while (lo < hi){ int mid = (lo+hi)>>1; if ((long long)rp[mid] < t0) lo = mid+1; else hi = mid; }
  int n0 = lo, n1;
  if (w == nwaves-1) n1 = N_NODES;
  else {
    lo = 0; hi = N_NODES;
    while (lo < hi){ int mid = (lo+hi)>>1; if ((long long)rp[mid] < t1) lo = mid+1; else hi = mid; }
    n1 = lo;
  }
  int nn = lane & 15, kg = lane >> 4;
  bf16x8 B[3][4];
  const u16* Wl = Wcol + (size_t)l*64*96;
#pragma unroll
  for (int t = 0; t < 4; t++)
#pragma unroll
    for (int kb = 0; kb < 3; kb++)
      B[kb][t] = *(const bf16x8*)(Wl + (size_t)(t*16+nn)*96 + kb*32 + kg*8);
  float s1[4] = {0,0,0,0}, s2[4] = {0,0,0,0};
  int rA = lane>>3, sA = lane&7;
  int rC = lane>>1, sC = lane&1;
  for (int n = n0; n < n1; n++){
    int b0 = rp[n], b1 = rp[n+1];
    float r0 = 0.f, r1 = 0.f, r2 = 0.f, r3 = 0.f;
    for (int base = b0; base < b1; base += 16){
      int rem = b1 - base; if (rem > 16) rem = 16;
      int eA = base + (rA < rem ? rA : rem-1);
      int2 pA = ((const int2*)perm2)[eA];
      uint4 vA = ((const uint4*)h_bf)[(size_t)pA.x*8 + sA];
      int rB = rA + 8;
      int eB = base + (rB < rem ? rB : rem-1);
      int2 pB = ((const int2*)perm2)[eB];
      uint4 vB = ((const uint4*)h_bf)[(size_t)pB.x*8 + sA];
      uint4 vC; int doC = (lane < 32);
      if (doC){
        int eC = base + (rC < rem ? rC : rem-1);
        int2 pC = ((const int2*)perm2)[eC];
        if (isbf){
          vC = ((const uint4*)ea)[(size_t)pC.y*2 + sC];
        } else {
          const float4* ef = (const float4*)ea;
          float4 f0 = ef[(size_t)pC.y*4 + sC*2];
          float4 f1 = ef[(size_t)pC.y*4 + sC*2 + 1];
          vC.x = (u32)f2bf(f0.x) | ((u32)f2bf(f0.y)<<16);
          vC.y = (u32)f2bf(f0.z) | ((u32)f2bf(f0.w)<<16);
          vC.z = (u32)f2bf(f1.x) | ((u32)f2bf(f1.y)<<16);
          vC.w = (u32)f2bf(f1.z) | ((u32)f2bf(f1.w)<<16);
        }
      }
      asm volatile("s_waitcnt lgkmcnt(0)" ::: "memory");
      *(uint4*)(A + rA*52 + sA*4) = vA;
      *(uint4*)(A + rB*52 + sA*4) = vB;
      if (doC) *(uint4*)(A + rC*52 + 32 + sC*4) = vC;
      asm volatile("s_waitcnt lgkmcnt(0)" ::: "memory");
      f32x4 a0 = {0,0,0,0}, a1 = {0,0,0,0}, a2 = {0,0,0,0}, a3 = {0,0,0,0};
#pragma unroll
      for (int kb = 0; kb < 3; kb++){
        bf16x8 af = *(const bf16x8*)(A + nn*52 + kb*16 + kg*4);
        a0 = __builtin_amdgcn_mfma_f32_16x16x32_bf16(af, B[kb][0], a0, 0,0,0);
        a1 = __builtin_amdgcn_mfma_f32_16x16x32_bf16(af, B[kb][1], a1, 0,0,0);
        a2 = __builtin_amdgcn_mfma_f32_16x16x32_bf16(af, B[kb][2], a2, 0,0,0);
        a3 = __builtin_amdgcn_mfma_f32_16x16x32_bf16(af, B[kb][3], a3, 0,0,0);
      }
      int rowbase = kg*4;
      float ts0 = 0.f, ts1 = 0.f, ts2 = 0.f, ts3 = 0.f;
#pragma unroll
      for (int j = 0; j < 4; j++){
        bool valid = (rowbase + j) < rem;
        float m0 = fmaxf(a0[j], 0.f); m0 = valid ? m0 : 0.f;
        float m1 = fmaxf(a1[j], 0.f); m1 = valid ? m1 : 0.f;
        float m2 = fmaxf(a2[j], 0.f); m2 = valid ? m2 : 0.f;
        float m3 = fmaxf(a3[j], 0.f); m3 = valid ? m3 : 0.f;
        ts0 += m0; ts1 += m1; ts2 += m2; ts3 += m3;
        s2[0] = fmaf(m0,m0,s2[0]); s2[1] = fmaf(m1,m1,s2[1]);
        s2[2] = fmaf(m2,m2,s2[2]); s2[3] = fmaf(m3,m3,s2[3]);
      }
      s1[0] += ts0; s1[1] += ts1; s1[2] += ts2; s1[3] += ts3;
      ts0 += __shfl_xor(ts0,16); ts0 += __shfl_xor(ts0,32);
      ts1 += __shfl_xor(ts1,16); ts1 += __shfl_xor(ts1,32);
      ts2 += __shfl_xor(ts2,16); ts2 += __shfl_xor(ts2,32);
      ts3 += __shfl_xor(ts3,16); ts3 += __shfl_xor(ts3,32);
      r0 += ts0; r1 += ts1; r2 += ts2; r3 += ts3;
    }
    float v = (kg==0) ? r0 : (kg==1) ? r1 : (kg==2) ? r2 : r3;
    agg[(size_t)n*64 + lane] = v;
  }
#pragma unroll
  for (int t = 0; t < 4; t++){
    atomicAdd(&bs[t*16+nn], s1[t]);
    atomicAdd(&bs[64+t*16+nn], s2[t]);
  }
  __syncthreads();
  if (tid < 128) atomicAdd(&stats[tid], bs[tid]);
}

// ---------------- BN finalize ----------------
__global__ void k_fin(const float* __restrict__ stats, const void* __restrict__ gamma,
                      const void* __restrict__ beta, float* __restrict__ aff,
                      float cnt_inv, int goff, const int* __restrict__ flagp){
  int isbf = *flagp; int c = threadIdx.x;
  float mu  = stats[c]      * cnt_inv;
  float var = stats[64 + c] * cnt_inv - mu*mu;
  float rs  = rsqrtf(var + 1e-5f);
  float g = ldf(gamma, (size_t)goff + c, isbf);
  float b = ldf(beta,  (size_t)goff + c, isbf);
  aff[c]      = g*rs;
  aff[64 + c] = b - g*mu*rs;
}

// ---------------- fused update (in-place on h) ----------------
__global__ void __launch_bounds__(256) k_upd(
    float* __restrict__ h, const float* __restrict__ agg,
    const float* __restrict__ degf, const float* __restrict__ maff,
    const void* __restrict__ uW, const void* __restrict__ ub,
    float* __restrict__ stats, const int* __restrict__ flagp, int l){
  __shared__ float bs[128];
  if (threadIdx.x < 128) bs[threadIdx.x] = 0.f;
  __syncthreads();
  int isbf = *flagp;
  int lane = threadIdx.x & 63;
  int gw = (blockIdx.x*blockDim.x + threadIdx.x) >> 6;
  int nw = (gridDim.x*blockDim.x) >> 6;
  float wa[64], wb[64]; float tv = 0.f;
#pragma unroll
  for (int k = 0; k < 64; k++){
    wa[k] = ldf(uW, (size_t)(l*128 + k)*64 + lane, isbf);
    float wk = ldf(uW, (size_t)(l*128 + 64 + k)*64 + lane, isbf);
    wb[k] = wk * maff[k];
    tv = fmaf(maff[64 + k], wk, tv);
  }
  float bias = ldf(ub, (size_t)l*64 + lane, isbf);
  float s1 = 0.f, s2 = 0.f;
  for (int n = gw; n < N_NODES; n += nw){
    const float4* hr = (const float4*)(h + (size_t)n*64);
    const float4* ar = (const float4*)(agg + (size_t)n*64);
    float a0 = fmaf(degf[n], tv, bias), a1 = 0.f, a2 = 0.f, a3 = 0.f;
#pragma unroll
    for (int q = 0; q < 8; q++){
      float4 a = hr[2*q+0];
      a0 = fmaf(a.x, wa[8*q+0], a0); a0 = fmaf(a.y, wa[8*q+1], a0);
      a0 = fmaf(a.z, wa[8*q+2], a0); a0 = fmaf(a.w, wa[8*q+3], a0);
      float4 b = hr[2*q+1];
      a1 = fmaf(b.x, wa[8*q+4], a1); a1 = fmaf(b.y, wa[8*q+5], a1);
      a1 = fmaf(b.z, wa[8*q+6], a1); a1 = fmaf(b.w, wa[8*q+7], a1);
      float4 c = ar[2*q+0];
      a2 = fmaf(c.x, wb[8*q+0], a2); a2 = fmaf(c.y, wb[8*q+1], a2);
      a2 = fmaf(c.z, wb[8*q+2], a2); a2 = fmaf(c.w, wb[8*q+3], a2);
      float4 d = ar[2*q+1];
      a3 = fmaf(d.x, wb[8*q+4], a3); a3 = fmaf(d.y, wb[8*q+5], a3);
      a3 = fmaf(d.z, wb[8*q+6], a3); a3 = fmaf(d.w, wb[8*q+7], a3);
    }
    float rl = fmaxf((a0 + a1) + (a2 + a3), 0.f);
    h[(size_t)n*64 + lane] = rl;
    s1 += rl;
    s2 = fmaf(rl, rl, s2);
  }
  atomicAdd(&bs[lane], s1);
  atomicAdd(&bs[64 + lane], s2);
  __syncthreads();
  if (threadIdx.x < 128) atomicAdd(&stats[threadIdx.x], bs[threadIdx.x]);
}

// ---------------- node BN apply (in-place) + bf16 dual store ----------------
__global__ void k_norm(float* __restrict__ h, const float* __restrict__ uaff,
                       u16* __restrict__ h_bf){
  int i = blockIdx.x*blockDim.x + threadIdx.x;
  if (i >= N_NODES*16) return;
  int c4 = i & 15;
  float4 sq = *(const float4*)(uaff + 4*c4);
  float4 tq = *(const float4*)(uaff + 64 + 4*c4);
  float4 v = ((const float4*)h)[i];
  float4 o;
  o.x = fmaf(sq.x, v.x, tq.x); o.y = fmaf(sq.y, v.y, tq.y);
  o.z = fmaf(sq.z, v.z, tq.z); o.w = fmaf(sq.w, v.w, tq.w);
  ((float4*)h)[i] = o;
  ushort4 ob;
  ob.x = f2bf(o.x); ob.y = f2bf(o.y); ob.z = f2bf(o.z); ob.w = f2bf(o.w);
  ((ushort4*)h_bf)[i] = ob;
}

// ---------------- global add pool ----------------
__global__ void k_pool(const float* __restrict__ h, const int* __restrict__ batch,
                       float* __restrict__ g){
  int lane = threadIdx.x & 63;
  int gw = (blockIdx.x*blockDim.x + threadIdx.x) >> 6;
  int nw = (gridDim.x*blockDim.x) >> 6;
  int chunk = (N_NODES + nw - 1) / nw;
  int n0 = gw*chunk;
  int n1 = n0 + chunk; if (n1 > N_NODES) n1 = N_NODES;
  int cur = -1; float acc = 0.f;
  for (int n = n0; n < n1; n++){
    int b = batch[n];
    float v = h[(size_t)n*64 + lane];
    if (b != cur){
      if (cur >= 0) atomicAdd(&g[(size_t)cur*64 + lane], acc);
      cur = b; acc = v;
    } else acc += v;
  }
  if (cur >= 0) atomicAdd(&g[(size_t)cur*64 + lane], acc);
}

// ---------------- readout ----------------
__global__ void k_read(const float* __restrict__ g, const void* __restrict__ r1W,
                       const void* __restrict__ r1b, const void* __restrict__ r2W,
                       const void* __restrict__ r2b, void* __restrict__ out,
                       const int* __restrict__ flagp){
  int isbf = *flagp;
  int lane = threadIdx.x;
  int gr = blockIdx.x;
  float w[64];
#pragma unroll
  for (int k = 0; k < 64; k++) w[k] = ldf(r1W, (size_t)k*64 + lane, isbf);
  float acc = ldf(r1b, lane, isbf);
  const float4* grow = (const float4*)(g + (size_t)gr*64);
#pragma unroll
  for (int q = 0; q < 16; q++){
    float4 a = grow[q];
    acc = fmaf(a.x, w[4*q+0], acc); acc = fmaf(a.y, w[4*q+1], acc);
    acc = fmaf(a.z, w[4*q+2], acc); acc = fmaf(a.w, w[4*q+3], acc);
  }
  float hid = fmaxf(acc, 0.f);
  float p = hid * ldf(r2W, lane, isbf);
  for (int o = 32; o; o >>= 1) p += __shfl_xor(p, o);
  if (lane == 0){
    float v = p + ldf(r2b, 0, isbf);
    if (isbf) ((__hip_bfloat16*)out)[gr] = __float2bfloat16(v);
    else      ((float*)out)[gr] = v;
  }
}

extern "C" void kernel_launch(void* const* d_in, const int* in_sizes, int n_in,
                              void* d_out, int out_size, void* d_ws, size_t ws_size,
                              hipStream_t stream){
  const void* x    = d_in[0];
  const void* ea   = d_in[1];
  const int*  ei   = (const int*)d_in[2];
  const int*  bt   = (const int*)d_in[3];
  const void* nW   = d_in[4];  const void* nb  = d_in[5];
  const void* eW   = d_in[6];  const void* eb  = d_in[7];
  const void* mW   = d_in[8];  const void* mb  = d_in[9];
  const void* mg   = d_in[10]; const void* mbe = d_in[11];
  const void* uW   = d_in[12]; const void* ub  = d_in[13];
  const void* ug   = d_in[14]; const void* ube = d_in[15];
  const void* r1W  = d_in[16]; const void* r1b = d_in[17];
  const void* r2W  = d_in[18]; const void* r2b = d_in[19];

  float* ws = (float*)d_ws;
  float* h        = ws + 0;                   // 6,400,000
  float* agg      = ws + 6400000;             // 6,400,000
  u16*   h_bf     = (u16*)(ws + 12800000);    // 3,200,000 fl
  int*   perm2    = (int*)(ws + 16000000);    // 3,200,000 ints
  float* degf     = ws + 19200000;            //   100,000
  int*   deg_i    = (int*)(ws + 19300000);    //   100,000
  float* g        = ws + 19400000;            //    64,000
  float* mstats   = ws + 19464000;            //       128
  float* ustats   = ws + 19464128;            //       128
  float* maff     = ws + 19464256;            //       128
  float* uaff     = ws + 19464384;            //       128
  int*   flag     = (int*)(ws + 19464512);    //        16
  u16*   Wcol     = (u16*)(ws + 19464528);    //     9,216 fl
  int*   row_ptr  = (int*)(ws + 19473744);    //   100,001
  int*   cursor   = (int*)(ws + 19573748);    //   100,000
  int*   bsum     = (int*)(ws + 19673748);    //       196
  int*   boff     = (int*)(ws + 19673944);    //       196 -> end 19,674,140 fl

  const int MM_BLOCKS = 2048;
  const int MM_WAVES  = MM_BLOCKS * 4;

  k_detect<<<1, 64, 0, stream>>>((const u32*)x, flag);
  hipMemsetAsync(ws + 19300000, 0, 164000*sizeof(float), stream);   // deg_i + g
  k_prep<<<3, 64, 0, stream>>>(eW, eb, mW, mb, Wcol, flag);
  k_node_emb<<<256, 256, 0, stream>>>(x, nW, nb, h, h_bf, flag);
  k_deg<<<512, 256, 0, stream>>>(ei, deg_i);
  k_scan1<<<196, 256, 0, stream>>>(deg_i, bsum);
  k_scan2<<<1, 256, 0, stream>>>(bsum, boff, row_ptr);
  k_scan3<<<196, 256, 0, stream>>>(deg_i, boff, row_ptr, cursor, degf);
  k_scatter<<<512, 256, 0, stream>>>(ei, cursor, perm2);

  for (int l = 0; l < 3; l++){
    hipMemsetAsync(mstats, 0, 256*sizeof(float), stream);           // mstats+ustats
    k_msgmm<<<MM_BLOCKS, 256, 0, stream>>>(h_bf, ea, row_ptr, perm2, Wcol,
                                           agg, mstats, flag, l, MM_WAVES);
    k_fin<<<1, 64, 0, stream>>>(mstats, mg, mbe, maff, 1.0f/(float)N_EDGES, l*64, flag);
    k_upd<<<1024, 256, 0, stream>>>(h, agg, degf, maff, uW, ub, ustats, flag, l);
    k_fin<<<1, 64, 0, stream>>>(ustats, ug, ube, uaff, 1.0f/(float)N_NODES, l*64, flag);
    k_norm<<<(N_NODES*16 + 255)/256, 256, 0, stream>>>(h, uaff, h_bf);
  }

  k_pool<<<128, 256, 0, stream>>>(h, bt, g);
  k_read<<<NUM_GRAPHS, 64, 0, stream>>>(g, r1W, r1b, r2W, r2b, d_out, flag);
}